// Round 4
// baseline (1986.525 us; speedup 1.0000x reference)
//
#include <hip/hip_runtime.h>
#include <hip/hip_bf16.h>
#include <math.h>

#define NBATCH 64
#define TSEQ   1000
#define DIN    257
#define HID    128
#define GATES  512   // 4*HID

typedef _Float16 h2    __attribute__((ext_vector_type(2)));
typedef _Float16 h4    __attribute__((ext_vector_type(4)));
typedef _Float16 half8 __attribute__((ext_vector_type(8)));
typedef float    f32x4 __attribute__((ext_vector_type(4)));

__device__ __forceinline__ float fast_sigmoid(float x) {
    return __builtin_amdgcn_rcpf(1.f + __expf(-x));
}
// branchless tanh: tanh(x) = 1 - 2/(exp(2x)+1), exact identity, valid all x
__device__ __forceinline__ float fast_tanh(float x) {
    const float e = __expf(2.f * x);
    return 1.f - 2.f * __builtin_amdgcn_rcpf(e + 1.f);
}
__device__ __forceinline__ half8 cvt8(const float* p) {
    const float4 a = *(const float4*)p;
    const float4 b = *(const float4*)(p + 4);
    half8 t;
    t[0] = (_Float16)a.x; t[1] = (_Float16)a.y;
    t[2] = (_Float16)a.z; t[3] = (_Float16)a.w;
    t[4] = (_Float16)b.x; t[5] = (_Float16)b.y;
    t[6] = (_Float16)b.z; t[7] = (_Float16)b.w;
    return t;
}

// ---------------------------------------------------------------------------
// f16 MFMA GEMM (unchanged): C = act(A @ W^T + b1 (+b2)), fp32 I/O.
// Used for pre1 (K=257) and the final mask GEMM.
// ---------------------------------------------------------------------------
#define BM 128
#define BN 64
#define BK 64
#define LDK 88

template<int ACT>
__global__ __launch_bounds__(256) void gemm_mfma(
    const float* __restrict__ A, const float* __restrict__ W,
    const float* __restrict__ b1, const float* __restrict__ b2,
    float* __restrict__ C, int M, int K, int Ncols)
{
    __shared__ _Float16 As[BM][LDK];
    __shared__ _Float16 Ws[BN][LDK];

    const int tid  = threadIdx.x;
    const int wave = tid >> 6;
    const int lane = tid & 63;
    const int r    = lane & 15;
    const int q    = lane >> 4;
    const int m0   = blockIdx.y * BM;
    const int n0   = blockIdx.x * BN;
    const int wm   = (wave >> 1) * 64;
    const int wn   = (wave & 1) * 32;

    const int r16 = tid >> 4;
    const int c4  = (tid & 15) * 4;

    f32x4 acc[4][2];
#pragma unroll
    for (int i = 0; i < 4; ++i)
#pragma unroll
        for (int j = 0; j < 2; ++j) acc[i][j] = f32x4{0.f, 0.f, 0.f, 0.f};

    for (int kc = 0; kc < K; kc += BK) {
        const int kg = kc + c4;
        const bool vec_ok = (kg + 4 <= K);

#pragma unroll
        for (int it = 0; it < 8; ++it) {
            const int row = it * 16 + r16;
            const float* src = A + (size_t)(m0 + row) * K + kg;
            _Float16 tmp[4];
            if (vec_ok) {
                const float4 u = *(const float4*)src;
                tmp[0] = (_Float16)u.x; tmp[1] = (_Float16)u.y;
                tmp[2] = (_Float16)u.z; tmp[3] = (_Float16)u.w;
            } else {
#pragma unroll
                for (int jj = 0; jj < 4; ++jj)
                    tmp[jj] = (kg + jj < K) ? (_Float16)src[jj] : (_Float16)0.f;
            }
            *(h4*)&As[row][c4] = *(h4*)tmp;
        }
#pragma unroll
        for (int it = 0; it < 4; ++it) {
            const int row  = it * 16 + r16;
            const int wrow = n0 + row;
            _Float16 tmp[4] = {(_Float16)0.f, (_Float16)0.f, (_Float16)0.f, (_Float16)0.f};
            if (wrow < Ncols) {
                const float* src = W + (size_t)wrow * K + kg;
                if (vec_ok) {
                    const float4 u = *(const float4*)src;
                    tmp[0] = (_Float16)u.x; tmp[1] = (_Float16)u.y;
                    tmp[2] = (_Float16)u.z; tmp[3] = (_Float16)u.w;
                } else {
#pragma unroll
                    for (int jj = 0; jj < 4; ++jj)
                        tmp[jj] = (kg + jj < K) ? (_Float16)src[jj] : (_Float16)0.f;
                }
            }
            *(h4*)&Ws[row][c4] = *(h4*)tmp;
        }
        __syncthreads();

#pragma unroll
        for (int s = 0; s < 2; ++s) {
            const int kb = s * 32 + q * 8;
            half8 af[4], wfr[2];
#pragma unroll
            for (int i = 0; i < 4; ++i)
                af[i] = *(const half8*)&As[wm + i * 16 + r][kb];
#pragma unroll
            for (int jj = 0; jj < 2; ++jj)
                wfr[jj] = *(const half8*)&Ws[wn + jj * 16 + r][kb];
#pragma unroll
            for (int i = 0; i < 4; ++i)
#pragma unroll
                for (int jj = 0; jj < 2; ++jj)
                    acc[i][jj] = __builtin_amdgcn_mfma_f32_16x16x32_f16(
                        af[i], wfr[jj], acc[i][jj], 0, 0, 0);
        }
        __syncthreads();
    }

#pragma unroll
    for (int i = 0; i < 4; ++i) {
#pragma unroll
        for (int jj = 0; jj < 2; ++jj) {
            const int col = n0 + wn + jj * 16 + r;
            if (col < Ncols) {
                const float bias = b1[col] + (b2 ? b2[col] : 0.f);
#pragma unroll
                for (int reg = 0; reg < 4; ++reg) {
                    const int row = m0 + wm + i * 16 + q * 4 + reg;
                    float v = acc[i][jj][reg] + bias;
                    if (ACT == 1) v = fast_sigmoid(v);
                    C[(size_t)row * Ncols + col] = v;
                }
            }
        }
    }
}

// ---------------------------------------------------------------------------
// R4: both LSTM layers fused in ONE block per chain (8 waves, 2/SIMD).
// Post-mortem of R3: the cross-block pipeline worked but paid ~800 cyc/step
// in agent fences (L2 writeback per chunk), acquire-poll cache invalidates,
// and a 131MB pre2 HBM round-trip (WRITE_SIZE 32->160MB). This version keeps
// the same software pipeline (L2 lags L1 by 8 steps) entirely INSIDE a block:
//   - per step t: every wave advances L1 step t (if t<1000) and L2 step t-8
//     (if t>=8). Gate rows split 8-way: wave u owns j in [16u,16u+16) for
//     BOTH layers (wf1,wf2 = 64+64 VGPR register-resident B-frags).
//   - h1 goes to LDS hbuf1 (dbl) + h1ck chunk history; every 8th step all 8
//     waves dense-GEMM h1ck @ Wih2^T (+bias2) -> pre2ck in LDS (16 MFMA/wave,
//     wih = 64 VGPR). Single-buffered: chunk c is written at the tail of step
//     8c+7 (after barrier A, before barrier B) and read during steps
//     8c+8..8c+15, strictly between barriers. No fences, no flags, no global
//     pre2 traffic.
//   - MFMA layouts identical to the verified R2/R3 kernels (A = replicated
//     h rows, B = weight rows in regs, D col=lane&15 row=4q+reg).
// Per-SIMD per-step: 2 waves x (16+16) matvec MFMA ~1240 cyc + 78 chunk
// + barrier ~= 1450 cyc for BOTH layers (vs R3's 1870 L1-side alone).
// ---------------------------------------------------------------------------
__global__ __launch_bounds__(512) void lstm_fused(
    const float* __restrict__ pre1, const float* __restrict__ states_in,
    const float* __restrict__ Whh1, const float* __restrict__ Whh2,
    const float* __restrict__ Wih2, const float* __restrict__ bih2,
    const float* __restrict__ bhh2,
    float* __restrict__ h2seq, float* __restrict__ states_out)
{
    const int n    = blockIdx.x;
    const int tid  = threadIdx.x;
    const int u    = tid >> 6;     // wave 0..7
    const int lane = tid & 63;
    const int r    = lane & 15;
    const int q    = lane >> 4;
    const int j    = 16 * u + r;   // this lane's output index (both layers)

    // ---- register-resident weights --------------------------------------
    // wf{1,2}[g][s]: B-frag row = 128g + j, k = s*32 + q*8 + e
    half8 wf1[4][4], wf2[4][4];
#pragma unroll
    for (int g = 0; g < 4; ++g) {
        const float* s1 = Whh1 + (size_t)(128 * g + j) * HID + q * 8;
        const float* s2 = Whh2 + (size_t)(128 * g + j) * HID + q * 8;
#pragma unroll
        for (int s = 0; s < 4; ++s) {
            wf1[g][s] = cvt8(s1 + s * 32);
            wf2[g][s] = cvt8(s2 + s * 32);
        }
    }
    // wih[fi][s]: B-frag row = 64u + 16fi + r (wave u owns pre2 cols 64u..+63)
    half8 wih[4][4];
    float bias2v[4];
#pragma unroll
    for (int fi = 0; fi < 4; ++fi) {
        const int row = 64 * u + 16 * fi + r;
        const float* sw = Wih2 + (size_t)row * HID + q * 8;
#pragma unroll
        for (int s = 0; s < 4; ++s) wih[fi][s] = cvt8(sw + s * 32);
        bias2v[fi] = bih2[row] + bhh2[row];
    }

    // ---- LDS -------------------------------------------------------------
    __shared__ __align__(16) _Float16 hbuf1[2][HID];
    __shared__ __align__(16) _Float16 hbuf2[2][HID];
    __shared__ __align__(16) _Float16 h1ck[8][136];   // chunk history, padded
    __shared__ __align__(16) float    pre2ck[8][GATES]; // 16 KB, single buffer

    float c1 = states_in[(size_t)(64 + n) * HID + j];
    float c2 = states_in[(size_t)(192 + n) * HID + j];
    if (tid < HID) {
        hbuf1[0][tid] = (_Float16)states_in[(size_t)n * HID + tid];
        hbuf2[0][tid] = (_Float16)states_in[(size_t)(128 + n) * HID + tid];
    }
    __syncthreads();

    // pre1 prefetch (t and t+1 rows resident; t+2 loaded per step)
    const float* pre_n = pre1 + (size_t)n * TSEQ * GATES;
    float pc0 = pre_n[j],           pc1 = pre_n[j + 128];
    float pc2 = pre_n[j + 256],     pc3 = pre_n[j + 384];
    float pn0 = pre_n[GATES + j],       pn1 = pre_n[GATES + j + 128];
    float pn2 = pre_n[GATES + j + 256], pn3 = pre_n[GATES + j + 384];

    const f32x4 Z = {0.f, 0.f, 0.f, 0.f};
    int cur1 = 0, cur2 = 0;

    for (int t = 0; t < TSEQ + 8; ++t) {
        const bool L1 = (t < TSEQ);
        const bool L2 = (t >= 8);
        const int  tp = t - 8;          // layer-2 step index

        float h1v = 0.f, h2v = 0.f;

        // ================= layer 1, step t =================
        if (L1) {
            const float p0 = pc0, p1 = pc1, p2 = pc2, p3 = pc3;
            pc0 = pn0; pc1 = pn1; pc2 = pn2; pc3 = pn3;
            if (t + 2 < TSEQ) {
                const float* pp = pre_n + (size_t)(t + 2) * GATES + j;
                pn0 = pp[0]; pn1 = pp[128]; pn2 = pp[256]; pn3 = pp[384];
            }

            half8 hx[4];
#pragma unroll
            for (int s = 0; s < 4; ++s)
                hx[s] = *(const half8*)&hbuf1[cur1][s * 32 + q * 8];

            f32x4 a[4];
#pragma unroll
            for (int g = 0; g < 4; ++g)
                a[g] = __builtin_amdgcn_mfma_f32_16x16x32_f16(hx[0], wf1[g][0], Z, 0, 0, 0);
#pragma unroll
            for (int s = 1; s < 4; ++s)
#pragma unroll
                for (int g = 0; g < 4; ++g)
                    a[g] = __builtin_amdgcn_mfma_f32_16x16x32_f16(hx[s], wf1[g][s], a[g], 0, 0, 0);

            const float gi = fast_sigmoid(a[0][0] + p0);
            const float gf = fast_sigmoid(a[1][0] + p1);
            const float gg = fast_tanh   (a[2][0] + p2);
            const float go = fast_sigmoid(a[3][0] + p3);
            c1  = gf * c1 + gi * gg;
            h1v = go * fast_tanh(c1);
        }

        // ================= layer 2, step t-8 =================
        if (L2) {
            half8 hy[4];
#pragma unroll
            for (int s = 0; s < 4; ++s)
                hy[s] = *(const half8*)&hbuf2[cur2][s * 32 + q * 8];

            const int ts = tp & 7;
            const float p0 = pre2ck[ts][j];
            const float p1 = pre2ck[ts][j + 128];
            const float p2 = pre2ck[ts][j + 256];
            const float p3 = pre2ck[ts][j + 384];

            f32x4 a[4];
#pragma unroll
            for (int g = 0; g < 4; ++g)
                a[g] = __builtin_amdgcn_mfma_f32_16x16x32_f16(hy[0], wf2[g][0], Z, 0, 0, 0);
#pragma unroll
            for (int s = 1; s < 4; ++s)
#pragma unroll
                for (int g = 0; g < 4; ++g)
                    a[g] = __builtin_amdgcn_mfma_f32_16x16x32_f16(hy[s], wf2[g][s], a[g], 0, 0, 0);

            const float gi = fast_sigmoid(a[0][0] + p0);
            const float gf = fast_sigmoid(a[1][0] + p1);
            const float gg = fast_tanh   (a[2][0] + p2);
            const float go = fast_sigmoid(a[3][0] + p3);
            c2  = gf * c2 + gi * gg;
            h2v = go * fast_tanh(c2);
        }

        // ================= writes, then barrier A =================
        if (L1) {
            if (q == 0) {
                hbuf1[cur1 ^ 1][j] = (_Float16)h1v;
                h1ck[t & 7][j]     = (_Float16)h1v;
            }
            if (t == TSEQ - 1) {
                if (q == 2) states_out[(size_t)n * HID + j]        = h1v;
                if (q == 3) states_out[(size_t)(64 + n) * HID + j] = c1;
            }
        }
        if (L2) {
            if (q == 0) hbuf2[cur2 ^ 1][j] = (_Float16)h2v;
            if (q == 1) h2seq[((size_t)n * TSEQ + tp) * HID + j] = h2v;
            if (tp == TSEQ - 1) {
                if (q == 2) states_out[(size_t)(128 + n) * HID + j] = h2v;
                if (q == 3) states_out[(size_t)(192 + n) * HID + j] = c2;
            }
        }
        __syncthreads();

        // ====== chunk tail (uniform cond): h1ck -> pre2ck dense GEMM ======
        if (L1 && (t & 7) == 7) {
            half8 ax[4];
#pragma unroll
            for (int s = 0; s < 4; ++s)
                ax[s] = *(const half8*)&h1ck[r & 7][s * 32 + q * 8];
            f32x4 gc[4];
#pragma unroll
            for (int fi = 0; fi < 4; ++fi)
                gc[fi] = __builtin_amdgcn_mfma_f32_16x16x32_f16(ax[0], wih[fi][0], Z, 0, 0, 0);
#pragma unroll
            for (int s = 1; s < 4; ++s)
#pragma unroll
                for (int fi = 0; fi < 4; ++fi)
                    gc[fi] = __builtin_amdgcn_mfma_f32_16x16x32_f16(ax[s], wih[fi][s], gc[fi], 0, 0, 0);
            // D: row=4q+reg = chunk step (q<2), col = 64u+16fi+r
            if (q < 2) {
#pragma unroll
                for (int fi = 0; fi < 4; ++fi)
#pragma unroll
                    for (int reg = 0; reg < 4; ++reg)
                        pre2ck[4 * q + reg][64 * u + 16 * fi + r] = gc[fi][reg] + bias2v[fi];
            }
            __syncthreads();
        }

        if (L1) cur1 ^= 1;
        if (L2) cur2 ^= 1;
    }
}

// ---------------------------------------------------------------------------
extern "C" void kernel_launch(void* const* d_in, const int* in_sizes, int n_in,
                              void* d_out, int out_size, void* d_ws, size_t ws_size,
                              hipStream_t stream)
{
    const float* x     = (const float*)d_in[0];
    const float* st_in = (const float*)d_in[1];
    const float* Wih1  = (const float*)d_in[2];
    const float* Whh1  = (const float*)d_in[3];
    const float* bih1  = (const float*)d_in[4];
    const float* bhh1  = (const float*)d_in[5];
    const float* Wih2  = (const float*)d_in[6];
    const float* Whh2  = (const float*)d_in[7];
    const float* bih2  = (const float*)d_in[8];
    const float* bhh2  = (const float*)d_in[9];
    const float* Wd    = (const float*)d_in[10];
    const float* bd    = (const float*)d_in[11];

    float* out_mask   = (float*)d_out;
    float* out_states = (float*)d_out + (size_t)NBATCH * TSEQ * DIN;

    const int M = NBATCH * TSEQ;
    float* bufA = (float*)d_ws;               // [M,512] pre1
    float* bufB = bufA + (size_t)M * GATES;   // [M,128] h2seq

    // K1: pre1 = x @ Wih1^T + bih1 + bhh1   (M=64000, K=257, N=512)
    gemm_mfma<0><<<dim3(GATES / BN, M / BM), 256, 0, stream>>>(
        x, Wih1, bih1, bhh1, bufA, M, DIN, GATES);

    // fused two-layer recurrence (replaces K2 + K3 + K4)
    lstm_fused<<<NBATCH, 512, 0, stream>>>(
        bufA, st_in, Whh1, Whh2, Wih2, bih2, bhh2, bufB, out_states);

    // K5: mask = sigmoid(h2seq @ Wd^T + bd)   (N=257)
    gemm_mfma<1><<<dim3((DIN + BN - 1) / BN, M / BM), 256, 0, stream>>>(
        bufB, Wd, bd, nullptr, out_mask, M, HID, DIN);
}

// Round 6
// 1097.361 us; speedup vs baseline: 1.8103x; 1.8103x over previous
//
#include <hip/hip_runtime.h>
#include <hip/hip_bf16.h>
#include <math.h>

#define NBATCH 64
#define TSEQ   1000
#define DIN    257
#define HID    128
#define GATES  512   // 4*HID
#define CH     40    // pipeline chunk (timesteps); 25 chunks of 40 = 1000
#define NCHUNK 25

typedef _Float16 h2    __attribute__((ext_vector_type(2)));
typedef _Float16 h4    __attribute__((ext_vector_type(4)));
typedef _Float16 half8 __attribute__((ext_vector_type(8)));
typedef float    f32x4 __attribute__((ext_vector_type(4)));

__device__ __forceinline__ float fast_sigmoid(float x) {
    return __builtin_amdgcn_rcpf(1.f + __expf(-x));
}
// branchless tanh: tanh(x) = 1 - 2/(exp(2x)+1), exact identity, valid all x
__device__ __forceinline__ float fast_tanh(float x) {
    const float e = __expf(2.f * x);
    return 1.f - 2.f * __builtin_amdgcn_rcpf(e + 1.f);
}
// R3-proven acquire poll (buffer_inv per iter is fine: reader has no other
// cached global state that matters; h1 loads after the acquire see fresh data)
__device__ __forceinline__ void wait_flag(const int* f, int need) {
    while (__hip_atomic_load(f, __ATOMIC_ACQUIRE, __HIP_MEMORY_SCOPE_AGENT) < need)
        __builtin_amdgcn_s_sleep(2);
}
__device__ __forceinline__ half8 cvt8(const float* p) {
    const float4 a = *(const float4*)p;
    const float4 b = *(const float4*)(p + 4);
    half8 t;
    t[0] = (_Float16)a.x; t[1] = (_Float16)a.y;
    t[2] = (_Float16)a.z; t[3] = (_Float16)a.w;
    t[4] = (_Float16)b.x; t[5] = (_Float16)b.y;
    t[6] = (_Float16)b.z; t[7] = (_Float16)b.w;
    return t;
}

// ---------------------------------------------------------------------------
// f16 MFMA GEMM (unchanged): C = act(A @ W^T + b1 (+b2)), fp32 I/O.
// Used for pre1 (K=257) and the final mask GEMM.
// ---------------------------------------------------------------------------
#define BM 128
#define BN 64
#define BK 64
#define LDK 88

template<int ACT>
__global__ __launch_bounds__(256) void gemm_mfma(
    const float* __restrict__ A, const float* __restrict__ W,
    const float* __restrict__ b1, const float* __restrict__ b2,
    float* __restrict__ C, int M, int K, int Ncols)
{
    __shared__ _Float16 As[BM][LDK];
    __shared__ _Float16 Ws[BN][LDK];

    const int tid  = threadIdx.x;
    const int wave = tid >> 6;
    const int lane = tid & 63;
    const int r    = lane & 15;
    const int q    = lane >> 4;
    const int m0   = blockIdx.y * BM;
    const int n0   = blockIdx.x * BN;
    const int wm   = (wave >> 1) * 64;
    const int wn   = (wave & 1) * 32;

    const int r16 = tid >> 4;
    const int c4  = (tid & 15) * 4;

    f32x4 acc[4][2];
#pragma unroll
    for (int i = 0; i < 4; ++i)
#pragma unroll
        for (int j = 0; j < 2; ++j) acc[i][j] = f32x4{0.f, 0.f, 0.f, 0.f};

    for (int kc = 0; kc < K; kc += BK) {
        const int kg = kc + c4;
        const bool vec_ok = (kg + 4 <= K);

#pragma unroll
        for (int it = 0; it < 8; ++it) {
            const int row = it * 16 + r16;
            const float* src = A + (size_t)(m0 + row) * K + kg;
            _Float16 tmp[4];
            if (vec_ok) {
                const float4 u = *(const float4*)src;
                tmp[0] = (_Float16)u.x; tmp[1] = (_Float16)u.y;
                tmp[2] = (_Float16)u.z; tmp[3] = (_Float16)u.w;
            } else {
#pragma unroll
                for (int j = 0; j < 4; ++j)
                    tmp[j] = (kg + j < K) ? (_Float16)src[j] : (_Float16)0.f;
            }
            *(h4*)&As[row][c4] = *(h4*)tmp;
        }
#pragma unroll
        for (int it = 0; it < 4; ++it) {
            const int row  = it * 16 + r16;
            const int wrow = n0 + row;
            _Float16 tmp[4] = {(_Float16)0.f, (_Float16)0.f, (_Float16)0.f, (_Float16)0.f};
            if (wrow < Ncols) {
                const float* src = W + (size_t)wrow * K + kg;
                if (vec_ok) {
                    const float4 u = *(const float4*)src;
                    tmp[0] = (_Float16)u.x; tmp[1] = (_Float16)u.y;
                    tmp[2] = (_Float16)u.z; tmp[3] = (_Float16)u.w;
                } else {
#pragma unroll
                    for (int j = 0; j < 4; ++j)
                        tmp[j] = (kg + j < K) ? (_Float16)src[j] : (_Float16)0.f;
                }
            }
            *(h4*)&Ws[row][c4] = *(h4*)tmp;
        }
        __syncthreads();

#pragma unroll
        for (int s = 0; s < 2; ++s) {
            const int kb = s * 32 + q * 8;
            half8 af[4], wfr[2];
#pragma unroll
            for (int i = 0; i < 4; ++i)
                af[i] = *(const half8*)&As[wm + i * 16 + r][kb];
#pragma unroll
            for (int j = 0; j < 2; ++j)
                wfr[j] = *(const half8*)&Ws[wn + j * 16 + r][kb];
#pragma unroll
            for (int i = 0; i < 4; ++i)
#pragma unroll
                for (int j = 0; j < 2; ++j)
                    acc[i][j] = __builtin_amdgcn_mfma_f32_16x16x32_f16(
                        af[i], wfr[j], acc[i][j], 0, 0, 0);
        }
        __syncthreads();
    }

#pragma unroll
    for (int i = 0; i < 4; ++i) {
#pragma unroll
        for (int j = 0; j < 2; ++j) {
            const int col = n0 + wn + j * 16 + r;
            if (col < Ncols) {
                const float bias = b1[col] + (b2 ? b2[col] : 0.f);
#pragma unroll
                for (int reg = 0; reg < 4; ++reg) {
                    const int row = m0 + wm + i * 16 + q * 4 + reg;
                    float v = acc[i][j][reg] + bias;
                    if (ACT == 1) v = fast_sigmoid(v);
                    C[(size_t)row * Ncols + col] = v;
                }
            }
        }
    }
}

// ---------------------------------------------------------------------------
// R6: R3's proven two-block pipeline + proven fence recipe (threadfence
// release / acquire poll), with the fence cost amortized and the handoff
// payload shrunk 8x.
//   - CH 8 -> 40: the per-chunk buffer_wbl2 (~6k cyc fixed, inferred from
//     R3's 930cyc/step overhead decomposition) amortizes to ~160 cyc/step.
//   - handoff = h1 chunk (f16, 10KB) instead of pre2 (f32, 80KB): layer-2
//     blocks compute pre2 themselves (register-resident Wih2, 96 MFMA/wave
//     per chunk = ~47 cyc/step, matrix pipe has headroom) into LDS pre2ck.
//     Deletes the 131MB pre2 HBM round-trip, the L1-side chunk GEMM and its
//     16KB store drain; L1 returns to R2's measured 1332 cyc/step + fence.
//   - h1g scratch lives in the out_mask region (overwritten later by K5).
// R5 post-mortem: relaxed agent-scope handoff (no fence) likely hung on flag
// visibility (XCD-private L2 never written back) -> container timeout.
// Reverted to the R3-proven synchronization; no relaxed tricks anywhere.
// ---------------------------------------------------------------------------
__global__ __launch_bounds__(256, 1) void lstm_mega(
    const float* __restrict__ pre1, const float* __restrict__ states_in,
    const float* __restrict__ Whh1, const float* __restrict__ Whh2,
    const float* __restrict__ Wih2, const float* __restrict__ bih2,
    const float* __restrict__ bhh2,
    _Float16* __restrict__ h1g,        // [M][128] f16 handoff (in mask region)
    float* __restrict__ h2seq,         // bufB: layer-2 hidden sequence
    float* __restrict__ states_out, int* __restrict__ flags)
{
    const int layer = blockIdx.x >> 6;
    const int n     = blockIdx.x & 63;
    const int tid   = threadIdx.x;
    const int w     = tid >> 6;
    const int lane  = tid & 63;
    const int r     = lane & 15;
    const int q     = lane >> 4;
    const int b     = q & 1;
    const int j     = 32 * w + 16 * b + r;   // this lane's output index
    const int h_row0 = layer ? 128 : 0;

    __shared__ __align__(16) _Float16 hbuf[2][HID];
    // pre2 chunk, layer-1 blocks only. +4 pad: write bank = (16q+4reg+r)%32
    // -> 2-way (free); read bank = (4ts+j)%32 -> conflict-free.
    __shared__ __align__(16) float pre2ck[CH][GATES + 4];

    // ---- recurrence weights: wf[g][b2][s], row = 128g + 32w + 16b2 + r
    const float* Whh = layer ? Whh2 : Whh1;
    half8 wf[4][2][4];
#pragma unroll
    for (int g = 0; g < 4; ++g)
#pragma unroll
        for (int b2 = 0; b2 < 2; ++b2) {
            const float* src = Whh + (size_t)(128 * g + 32 * w + 16 * b2 + r) * HID + q * 8;
#pragma unroll
            for (int s = 0; s < 4; ++s) wf[g][b2][s] = cvt8(src + s * 32);
        }

    // ---- layer-2 extra: Wih2 B-frags (wave w owns pre2 cols 128w..128w+127)
    half8 wih[8][4];
    float bias2v[8];
    if (layer == 1) {
#pragma unroll
        for (int fi = 0; fi < 8; ++fi) {
            const int row = 128 * w + 16 * fi + r;
            const float* src = Wih2 + (size_t)row * HID + q * 8;
#pragma unroll
            for (int s = 0; s < 4; ++s) wih[fi][s] = cvt8(src + s * 32);
            bias2v[fi] = bih2[row] + bhh2[row];
        }
    }

    float c_r = states_in[(size_t)(h_row0 + 64 + n) * HID + j];
    if (tid < HID)
        hbuf[0][tid] = (_Float16)states_in[(size_t)(h_row0 + n) * HID + tid];
    __syncthreads();

    // layer-1: pre1 prefetch registers
    const float* pre_n = pre1 + (size_t)n * TSEQ * GATES;
    float pc0 = 0.f, pc1 = 0.f, pc2 = 0.f, pc3 = 0.f;
    float pn0 = 0.f, pn1 = 0.f, pn2 = 0.f, pn3 = 0.f;
    if (layer == 0) {
        pc0 = pre_n[j];           pc1 = pre_n[j + 128];
        pc2 = pre_n[j + 256];     pc3 = pre_n[j + 384];
        pn0 = pre_n[GATES + j];       pn1 = pre_n[GATES + j + 128];
        pn2 = pre_n[GATES + j + 256]; pn3 = pre_n[GATES + j + 384];
    }

    const f32x4 Z = {0.f, 0.f, 0.f, 0.f};
    int cur = 0, ts = 0, ck = 0;   // step-within-chunk, chunk index

    for (int t = 0; t < TSEQ; ++t) {
        // ==== layer-2 chunk head: wait for h1 chunk ck, compute pre2ck ====
        if (layer == 1 && ts == 0) {
            wait_flag(flags + n, ck + 1);   // ACQUIRE: h1g chunk ck visible
            const _Float16* hbase = h1g + ((size_t)n * TSEQ + (size_t)ck * CH) * HID;
            // 40 rows = m-tiles {0..15, 16..31, 32..39 (r&7 replicated)}
#pragma unroll
            for (int mt = 0; mt < 3; ++mt) {
                const int mrow = (mt < 2) ? (mt * 16 + r) : (32 + (r & 7));
                const _Float16* src = hbase + (size_t)mrow * HID + q * 8;
                half8 ax[4];
#pragma unroll
                for (int s = 0; s < 4; ++s)
                    ax[s] = *(const half8*)(src + s * 32);
                f32x4 gacc[8];
#pragma unroll
                for (int fi = 0; fi < 8; ++fi)
                    gacc[fi] = __builtin_amdgcn_mfma_f32_16x16x32_f16(
                        ax[0], wih[fi][0], Z, 0, 0, 0);
#pragma unroll
                for (int s = 1; s < 4; ++s)
#pragma unroll
                    for (int fi = 0; fi < 8; ++fi)
                        gacc[fi] = __builtin_amdgcn_mfma_f32_16x16x32_f16(
                            ax[s], wih[fi][s], gacc[fi], 0, 0, 0);
                // D: step = mt*16 + 4q + reg, col = 128w + 16fi + r
                if (mt < 2 || q < 2) {
#pragma unroll
                    for (int fi = 0; fi < 8; ++fi)
#pragma unroll
                        for (int reg = 0; reg < 4; ++reg)
                            pre2ck[mt * 16 + 4 * q + reg][128 * w + 16 * fi + r] =
                                gacc[fi][reg] + bias2v[fi];
                }
            }
            __syncthreads();
        }

        // ==== gate pre-activations ====
        float p0, p1, p2, p3;
        if (layer == 0) {
            p0 = pc0; p1 = pc1; p2 = pc2; p3 = pc3;
            pc0 = pn0; pc1 = pn1; pc2 = pn2; pc3 = pn3;
            if (t + 2 < TSEQ) {
                const float* pp = pre_n + (size_t)(t + 2) * GATES + j;
                pn0 = pp[0]; pn1 = pp[128]; pn2 = pp[256]; pn3 = pp[384];
            }
        } else {
            p0 = pre2ck[ts][j];
            p1 = pre2ck[ts][j + 128];
            p2 = pre2ck[ts][j + 256];
            p3 = pre2ck[ts][j + 384];
        }

        // ==== recurrent matvec (MFMA) ====
        half8 hx[4];
#pragma unroll
        for (int s = 0; s < 4; ++s)
            hx[s] = *(const half8*)&hbuf[cur][s * 32 + q * 8];

        f32x4 acc[4][2];
#pragma unroll
        for (int g = 0; g < 4; ++g)
#pragma unroll
            for (int b2 = 0; b2 < 2; ++b2)
                acc[g][b2] = __builtin_amdgcn_mfma_f32_16x16x32_f16(
                    hx[0], wf[g][b2][0], Z, 0, 0, 0);
#pragma unroll
        for (int s = 1; s < 4; ++s)
#pragma unroll
            for (int g = 0; g < 4; ++g)
#pragma unroll
                for (int b2 = 0; b2 < 2; ++b2)
                    acc[g][b2] = __builtin_amdgcn_mfma_f32_16x16x32_f16(
                        hx[s], wf[g][b2][s], acc[g][b2], 0, 0, 0);

        const float A0 = (b ? acc[0][1][0] : acc[0][0][0]) + p0;
        const float A1 = (b ? acc[1][1][0] : acc[1][0][0]) + p1;
        const float A2 = (b ? acc[2][1][0] : acc[2][0][0]) + p2;
        const float A3 = (b ? acc[3][1][0] : acc[3][0][0]) + p3;

        const float gi = fast_sigmoid(A0);
        const float gf = fast_sigmoid(A1);
        const float gg = fast_tanh(A2);
        const float go = fast_sigmoid(A3);

        const float cn = gf * c_r + gi * gg;
        const float hh = go * fast_tanh(cn);
        c_r = cn;

        // ==== state writes ====
        if (q < 2) {
            hbuf[cur ^ 1][j] = (_Float16)hh;
            if (t == TSEQ - 1)
                states_out[(size_t)(h_row0 + 64 + n) * HID + j] = cn;
        } else {
            if (layer == 0)
                h1g[((size_t)n * TSEQ + t) * HID + j] = (_Float16)hh;
            else
                h2seq[((size_t)n * TSEQ + t) * HID + j] = hh;
            if (t == TSEQ - 1)
                states_out[(size_t)(h_row0 + n) * HID + j] = hh;
        }
        __syncthreads();   // drains vmcnt(0) per wave: chunk stores complete

        // ==== layer-1 chunk tail: publish chunk ck (proven fence recipe) ====
        if (layer == 0 && ts == CH - 1 && tid == 0) {
            __threadfence();   // agent release (wbl2): h1g chunk ck visible
            __hip_atomic_store(flags + n, ck + 1,
                               __ATOMIC_RELAXED, __HIP_MEMORY_SCOPE_AGENT);
        }

        if (++ts == CH) { ts = 0; ++ck; }
        cur ^= 1;
    }
}

// ---------------------------------------------------------------------------
extern "C" void kernel_launch(void* const* d_in, const int* in_sizes, int n_in,
                              void* d_out, int out_size, void* d_ws, size_t ws_size,
                              hipStream_t stream)
{
    const float* x     = (const float*)d_in[0];
    const float* st_in = (const float*)d_in[1];
    const float* Wih1  = (const float*)d_in[2];
    const float* Whh1  = (const float*)d_in[3];
    const float* bih1  = (const float*)d_in[4];
    const float* bhh1  = (const float*)d_in[5];
    const float* Wih2  = (const float*)d_in[6];
    const float* Whh2  = (const float*)d_in[7];
    const float* bih2  = (const float*)d_in[8];
    const float* bhh2  = (const float*)d_in[9];
    const float* Wd    = (const float*)d_in[10];
    const float* bd    = (const float*)d_in[11];

    float* out_mask   = (float*)d_out;
    float* out_states = (float*)d_out + (size_t)NBATCH * TSEQ * DIN;

    const int M = NBATCH * TSEQ;
    float* bufA = (float*)d_ws;               // [M,512] pre1
    float* bufB = bufA + (size_t)M * GATES;   // [M,128] h2seq

    // scratch in the mask output region (overwritten by K5 afterwards):
    //   h1g: [M,128] f16 = 16.4MB at the start; flags: 64 ints at the end.
    _Float16* h1g = (_Float16*)out_mask;
    int* flags = (int*)(out_mask + (size_t)NBATCH * TSEQ * DIN) - 64;
    hipMemsetAsync(flags, 0, 64 * sizeof(int), stream);

    // K1: pre1 = x @ Wih1^T + bih1 + bhh1   (M=64000, K=257, N=512)
    gemm_mfma<0><<<dim3(GATES / BN, M / BM), 256, 0, stream>>>(
        x, Wih1, bih1, bhh1, bufA, M, DIN, GATES);

    // fused pipelined L1 rec -> h1 handoff -> (pre2 on reader) -> L2 rec
    lstm_mega<<<128, 256, 0, stream>>>(
        bufA, st_in, Whh1, Whh2, Wih2, bih2, bhh2, h1g, bufB, out_states, flags);

    // K5: mask = sigmoid(h2seq @ Wd^T + bd)   (N=257)
    gemm_mfma<1><<<dim3((DIN + BN - 1) / BN, M / BM), 256, 0, stream>>>(
        bufB, Wd, bd, nullptr, out_mask, M, HID, DIN);
}